// Round 5
// baseline (665.745 us; speedup 1.0000x reference)
//
#include <hip/hip_runtime.h>
#include <cmath>

typedef _Float16 f16;
typedef f16 f16x8 __attribute__((ext_vector_type(8)));
typedef f16 f16x4 __attribute__((ext_vector_type(4)));
typedef float f32x4 __attribute__((ext_vector_type(4)));

#define Ln 4096
#define Dn 256
#define NEGV (-1e30f)

// workspace byte offsets (~81.6 MiB; 96 MiB proven available in R1)
#define B_QH   0ul           // fp16 Q = 16MiB (dead after flash; ath overlays)
#define B_KH   (16ul << 20)  // fp16 K = 16MiB (dead after flash; t overlays)
#define B_VT   (32ul << 20)  // fp16 V^T [8][256][4096] = 16MiB (dead after flash)
#define B_OP   (48ul << 20)  // fp16 partial O, 2 splits x 16MiB = 32MiB
#define B_ML   (80ul << 20)  // float2 (m,l) [2][8][4096] = 512KiB
#define B_ATH  0ul           // fp16 attn = 16MiB, overlays Qh
#define B_T    (16ul << 20)  // fp32 t = 32MiB, overlays Kh+Vt
#define B_LENS (81ul << 20)  // lens[8]
#define B_SUMS (B_LENS + 128)         // 512 floats
#define B_WQT  (B_LENS + 4096)        // fp16 WqT [256n][256k] = 128KiB
#define B_WKT  (B_WQT + (128ul<<10))
#define B_WVT  (B_WKT + (128ul<<10))
#define B_WTT  (B_WVT + (128ul<<10))

__device__ __forceinline__ void async_ld16(f16* lds, const f16* g) {
  __builtin_amdgcn_global_load_lds((const __attribute__((address_space(1))) unsigned int*)g,
                                   (__attribute__((address_space(3))) unsigned int*)lds, 16, 0, 0);
}

__global__ __launch_bounds__(256) void k_init(const int* __restrict__ mask, int* __restrict__ lens,
                                              float* __restrict__ sums) {
  const int b = blockIdx.x, tid = threadIdx.x;
  if (b == 0) { sums[tid] = 0.f; sums[256 + tid] = 0.f; }
  int cnt = 0;
  for (int l = tid; l < Ln; l += 256) cnt += (mask[b * Ln + l] != 0) ? 1 : 0;
  __shared__ int red[256];
  red[tid] = cnt;
  __syncthreads();
  for (int s = 128; s > 0; s >>= 1) {
    if (tid < s) red[tid] += red[tid + s];
    __syncthreads();
  }
  if (tid == 0) lens[b] = red[0];
}

// transpose+cast weights: WT[n][k] = (f16)W[k][n]
__global__ __launch_bounds__(256) void k_cast_w(const float* __restrict__ W0, const float* __restrict__ W1,
                                                const float* __restrict__ W2, const float* __restrict__ W3,
                                                f16* __restrict__ T0, f16* __restrict__ T1,
                                                f16* __restrict__ T2, f16* __restrict__ T3) {
  const float* Ws[4] = {W0, W1, W2, W3};
  f16* Ts[4] = {T0, T1, T2, T3};
  const float* W = Ws[blockIdx.x];
  f16* T = Ts[blockIdx.x];
  const int k0 = blockIdx.y * 64, n0 = blockIdx.z * 64;
  const int tid = threadIdx.x;
  __shared__ float ld[64][65];
#pragma unroll
  for (int i = 0; i < 16; ++i) {
    int flat = i * 256 + tid;
    int r = flat >> 6, c = flat & 63;
    ld[r][c] = W[(size_t)(k0 + r) * Dn + n0 + c];
  }
  __syncthreads();
#pragma unroll
  for (int i = 0; i < 16; ++i) {
    int flat = i * 256 + tid;
    int r = flat >> 6, c = flat & 63;
    T[(size_t)(n0 + r) * Dn + k0 + c] = (f16)ld[c][r];
  }
}

// Fused x-cast + QKV projection (proven R4 version).
__global__ __launch_bounds__(256) void k_qkv(const float* __restrict__ x, const f16* __restrict__ WqT,
                                             const f16* __restrict__ WkT, const f16* __restrict__ WvT,
                                             f16* __restrict__ Qh, f16* __restrict__ Kh,
                                             f16* __restrict__ Vt) {
  __shared__ f16 sA[64 * 256];
  __shared__ f16 vts[256 * 72];
  const int tid = threadIdx.x;
  const int lane = tid & 63;
  const int ln15 = lane & 15;
  const int quad = lane >> 4;
  const int wave = tid >> 6;
  const int wr = wave >> 1;
  const int wn = wave & 1;
  const size_t row0 = (size_t)blockIdx.x * 64;

  {
    const float* src = x + row0 * Dn;
#pragma unroll
    for (int i = 0; i < 8; ++i) {
      int flat = i * 256 + tid;
      int r = flat >> 5, p = flat & 31, g = p ^ (r & 7);
      float4 lo = *(const float4*)&src[r * Dn + g * 8];
      float4 hi = *(const float4*)&src[r * Dn + g * 8 + 4];
      f16x8 h = {(f16)lo.x, (f16)lo.y, (f16)lo.z, (f16)lo.w,
                 (f16)hi.x, (f16)hi.y, (f16)hi.z, (f16)hi.w};
      *(f16x8*)&sA[flat * 8] = h;
    }
  }
  __syncthreads();

  f16x8 af[2][8];
#pragma unroll
  for (int rg = 0; rg < 2; ++rg) {
    int r = wr * 32 + rg * 16 + ln15;
    int sw = r & 7;
#pragma unroll
    for (int c = 0; c < 8; ++c)
      af[rg][c] = *(const f16x8*)&sA[r * 256 + (((c * 4 + quad) ^ sw) << 3)];
  }

  const f16* Bm[3] = {WqT, WkT, WvT};
  for (int m = 0; m < 3; ++m) {
    const f16* B = Bm[m];
    f32x4 acc0[8], acc1[8];
#pragma unroll
    for (int nt = 0; nt < 8; ++nt) {
#pragma unroll
      for (int i = 0; i < 4; ++i) { acc0[nt][i] = 0.f; acc1[nt][i] = 0.f; }
    }
#pragma unroll
    for (int c = 0; c < 8; ++c) {
#pragma unroll
      for (int nt = 0; nt < 8; ++nt) {
        f16x8 bf = *(const f16x8*)&B[(size_t)(wn * 128 + nt * 16 + ln15) * 256 + c * 32 + quad * 8];
        acc0[nt] = __builtin_amdgcn_mfma_f32_16x16x32_f16(af[0][c], bf, acc0[nt], 0, 0, 0);
        acc1[nt] = __builtin_amdgcn_mfma_f32_16x16x32_f16(af[1][c], bf, acc1[nt], 0, 0, 0);
      }
    }
    if (m < 2) {
      f16* dst = (m == 0) ? Qh : Kh;
#pragma unroll
      for (int nt = 0; nt < 8; ++nt) {
        int col = wn * 128 + nt * 16 + ln15;
#pragma unroll
        for (int i = 0; i < 4; ++i) {
          dst[(row0 + wr * 32 + quad * 4 + i) * (size_t)Dn + col] = (f16)acc0[nt][i];
          dst[(row0 + wr * 32 + 16 + quad * 4 + i) * (size_t)Dn + col] = (f16)acc1[nt][i];
        }
      }
    } else {
#pragma unroll
      for (int nt = 0; nt < 8; ++nt) {
        int ch = wn * 128 + nt * 16 + ln15;
#pragma unroll
        for (int i = 0; i < 4; ++i) {
          vts[ch * 72 + wr * 32 + quad * 4 + i] = (f16)acc0[nt][i];
          vts[ch * 72 + wr * 32 + 16 + quad * 4 + i] = (f16)acc1[nt][i];
        }
      }
      __syncthreads();
      const int b = (int)(row0 >> 12);
      const int l0 = (int)(row0 & 4095);
      f16* vdst = Vt + (size_t)b * Dn * Ln + (size_t)tid * Ln + l0;
#pragma unroll
      for (int j = 0; j < 8; ++j)
        *(f16x8*)(vdst + 8 * j) = *(const f16x8*)&vts[tid * 72 + 8 * j];
    }
  }
}

// Flash attention v3: 128q/block (4 waves x 32q), 2-way key split, 32-key
// double-buffered tiles, 1 barrier/tile, wave-local softmax. Writes normalized
// partial O (fp16) + per-row (m,l) for the combine pass.
__global__ __launch_bounds__(256, 2) void k_flash(const f16* __restrict__ Qh, const f16* __restrict__ Kh,
                                                  const f16* __restrict__ Vt, const int* __restrict__ lens,
                                                  f16* __restrict__ Op, float2* __restrict__ Ml) {
  const int b = blockIdx.z;
  const int s = blockIdx.y;
  const int len = lens[b];
  const int i0 = blockIdx.x * 128;
  if (i0 >= len) return;
  const int tid = threadIdx.x;
  const int lane = tid & 63;
  const int ln15 = lane & 15;
  const int quad = lane >> 4;
  const int w = tid >> 6;

  __shared__ f16 sK[2][32 * 256];    // 2 x 16KiB, XOR-swizzled 16B granules
  __shared__ f16 sV[2][256 * 32];    // 2 x 16KiB, V^T [ch][key], swizzled
  __shared__ f16 sP[4][2][16 * 40];  // per-wave P tiles

  const f16* Qb = Qh + (size_t)b * Ln * Dn;
  const f16* Kb = Kh + (size_t)b * Ln * Dn;
  const f16* Vb = Vt + (size_t)b * Dn * Ln;

  const int T = (len + 31) >> 5;
  const int h = T >> 1;
  const int t0 = s ? h : 0;
  const int t1 = s ? T : h;

  // Q A-fragments: rows i0 + w*32 + qt*16 + ln15
  f16x8 qf[2][8];
#pragma unroll
  for (int qt = 0; qt < 2; ++qt) {
    const f16* qrow = Qb + (size_t)(i0 + w * 32 + qt * 16 + ln15) * Dn + quad * 8;
#pragma unroll
    for (int c = 0; c < 8; ++c) qf[qt][c] = *(const f16x8*)(qrow + c * 32);
  }

  f32x4 oAcc[2][16];
#pragma unroll
  for (int qt = 0; qt < 2; ++qt)
#pragma unroll
    for (int nf = 0; nf < 16; ++nf) { oAcc[qt][nf][0] = 0.f; oAcc[qt][nf][1] = 0.f; oAcc[qt][nf][2] = 0.f; oAcc[qt][nf][3] = 0.f; }
  float m_i[2][4], l_i[2][4];
#pragma unroll
  for (int qt = 0; qt < 2; ++qt)
#pragma unroll
    for (int i = 0; i < 4; ++i) { m_i[qt][i] = -INFINITY; l_i[qt][i] = 0.f; }

  // prologue: stage tile t0 into buf 0
  {
    const f16* ksrc = Kb + (size_t)(t0 << 5) * Dn;
#pragma unroll
    for (int i = 0; i < 4; ++i) {
      int flat = i * 256 + tid;
      int r = flat >> 5, p = flat & 31, g = p ^ (r & 7);
      async_ld16(&sK[0][(i * 256 + (tid & 192)) * 8], ksrc + r * Dn + g * 8);
    }
#pragma unroll
    for (int i = 0; i < 4; ++i) {
      int flat = i * 256 + tid;
      int r = flat >> 2, p = flat & 3, g = p ^ (r & 3);
      async_ld16(&sV[0][(i * 256 + (tid & 192)) * 8], Vb + (size_t)r * Ln + (t0 << 5) + g * 8);
    }
  }

  for (int t = t0, it = 0; t < t1; ++t, ++it) {
    const int buf = it & 1;
    __syncthreads();  // drains stage(t); all waves done with buf^1
    if (t + 1 < t1) {
      const f16* ksrc = Kb + (size_t)((t + 1) << 5) * Dn;
#pragma unroll
      for (int i = 0; i < 4; ++i) {
        int flat = i * 256 + tid;
        int r = flat >> 5, p = flat & 31, g = p ^ (r & 7);
        async_ld16(&sK[buf ^ 1][(i * 256 + (tid & 192)) * 8], ksrc + r * Dn + g * 8);
      }
#pragma unroll
      for (int i = 0; i < 4; ++i) {
        int flat = i * 256 + tid;
        int r = flat >> 2, p = flat & 3, g = p ^ (r & 3);
        async_ld16(&sV[buf ^ 1][(i * 256 + (tid & 192)) * 8], Vb + (size_t)r * Ln + ((t + 1) << 5) + g * 8);
      }
    }

    // ---- S = Q K^T on buf ----
    f32x4 sAcc[2][2];
#pragma unroll
    for (int qt = 0; qt < 2; ++qt)
#pragma unroll
      for (int kt = 0; kt < 2; ++kt) { sAcc[qt][kt][0] = 0.f; sAcc[qt][kt][1] = 0.f; sAcc[qt][kt][2] = 0.f; sAcc[qt][kt][3] = 0.f; }
    const int sw0 = ln15 & 7;
#pragma unroll
    for (int c = 0; c < 8; ++c) {
      int gk = (((c * 4 + quad) ^ sw0) << 3);
      f16x8 b0 = *(const f16x8*)&sK[buf][ln15 * 256 + gk];
      f16x8 b1 = *(const f16x8*)&sK[buf][(16 + ln15) * 256 + gk];
      sAcc[0][0] = __builtin_amdgcn_mfma_f32_16x16x32_f16(qf[0][c], b0, sAcc[0][0], 0, 0, 0);
      sAcc[0][1] = __builtin_amdgcn_mfma_f32_16x16x32_f16(qf[0][c], b1, sAcc[0][1], 0, 0, 0);
      sAcc[1][0] = __builtin_amdgcn_mfma_f32_16x16x32_f16(qf[1][c], b0, sAcc[1][0], 0, 0, 0);
      sAcc[1][1] = __builtin_amdgcn_mfma_f32_16x16x32_f16(qf[1][c], b1, sAcc[1][1], 0, 0, 0);
    }

    // ---- online softmax (wave-local) ----
    const int j0 = t << 5;
    const bool iv0 = (j0 + ln15) >= len;
    const bool iv1 = (j0 + 16 + ln15) >= len;
    float alpha[2][4];
    bool need = false;
#pragma unroll
    for (int qt = 0; qt < 2; ++qt) {
#pragma unroll
      for (int i = 0; i < 4; ++i) {
        float a0 = iv0 ? NEGV : sAcc[qt][0][i];
        float a1 = iv1 ? NEGV : sAcc[qt][1][i];
        float rm = fmaxf(a0, a1);
        rm = fmaxf(rm, __shfl_xor(rm, 1));
        rm = fmaxf(rm, __shfl_xor(rm, 2));
        rm = fmaxf(rm, __shfl_xor(rm, 4));
        rm = fmaxf(rm, __shfl_xor(rm, 8));
        float mo = m_i[qt][i];
        float mn = fmaxf(mo, rm);
        float al = __expf(mo - mn);
        float p0 = __expf(a0 - mn);
        float p1 = __expf(a1 - mn);
        float rs = p0 + p1;
        rs += __shfl_xor(rs, 1);
        rs += __shfl_xor(rs, 2);
        rs += __shfl_xor(rs, 4);
        rs += __shfl_xor(rs, 8);
        l_i[qt][i] = l_i[qt][i] * al + rs;
        m_i[qt][i] = mn;
        alpha[qt][i] = al;
        need |= (al < 1.0f);
        sP[w][qt][(quad * 4 + i) * 40 + ln15] = (f16)p0;
        sP[w][qt][(quad * 4 + i) * 40 + 16 + ln15] = (f16)p1;
      }
    }
    if (__any(need ? 1 : 0)) {
#pragma unroll
      for (int qt = 0; qt < 2; ++qt)
#pragma unroll
        for (int nf = 0; nf < 16; ++nf)
#pragma unroll
          for (int i = 0; i < 4; ++i) oAcc[qt][nf][i] *= alpha[qt][i];
    }

    // ---- PV on buf ----
    f16x8 pa0 = *(const f16x8*)&sP[w][0][ln15 * 40 + quad * 8];
    f16x8 pa1 = *(const f16x8*)&sP[w][1][ln15 * 40 + quad * 8];
#pragma unroll
    for (int nf = 0; nf < 16; ++nf) {
      int rv = nf * 16 + ln15;
      f16x8 vb = *(const f16x8*)&sV[buf][rv * 32 + ((quad ^ (rv & 3)) << 3)];
      oAcc[0][nf] = __builtin_amdgcn_mfma_f32_16x16x32_f16(pa0, vb, oAcc[0][nf], 0, 0, 0);
      oAcc[1][nf] = __builtin_amdgcn_mfma_f32_16x16x32_f16(pa1, vb, oAcc[1][nf], 0, 0, 0);
    }
  }

  // epilogue: normalized partial O + (m,l)
  f16* Ob = Op + ((size_t)s * 8 + b) * Ln * Dn;
  float2* Mb = Ml + ((size_t)s * 8 + b) * Ln;
#pragma unroll
  for (int qt = 0; qt < 2; ++qt) {
#pragma unroll
    for (int i = 0; i < 4; ++i) {
      int row = i0 + w * 32 + qt * 16 + quad * 4 + i;
      if (row < len) {
        float inv = 1.f / l_i[qt][i];
#pragma unroll
        for (int nf = 0; nf < 16; ++nf)
          Ob[(size_t)row * Dn + nf * 16 + ln15] = (f16)(oAcc[qt][nf][i] * inv);
        if (ln15 == 0) Mb[row] = make_float2(m_i[qt][i], l_i[qt][i]);
      }
    }
  }
}

// merge the 2 key-split partials: out = sum_s w_s * O_s, w_s = exp(m_s-m*)*l_s (normalized)
__global__ __launch_bounds__(256) void k_combine(const f16* __restrict__ Op, const float2* __restrict__ Ml,
                                                 const int* __restrict__ lens, f16* __restrict__ ath) {
  const size_t idx = (size_t)blockIdx.x * 256 + threadIdx.x;  // f16x4 chunk
  const size_t rowg = idx >> 6;
  const int b = (int)(rowg >> 12);
  const int row = (int)(rowg & 4095);
  if (row >= lens[b]) return;
  const size_t SS = (size_t)8 * Ln * Dn;
  float2 ml0 = Ml[(size_t)b * Ln + row];
  float2 ml1 = Ml[(size_t)8 * Ln + (size_t)b * Ln + row];
  float ms = fmaxf(ml0.x, ml1.x);
  float w0 = __expf(ml0.x - ms) * ml0.y;
  float w1 = __expf(ml1.x - ms) * ml1.y;
  float inv = 1.f / (w0 + w1);
  w0 *= inv; w1 *= inv;
  const size_t off = rowg * Dn + (idx & 63) * 4;
  f16x4 p0 = *(const f16x4*)&Op[off];
  f16x4 p1 = *(const f16x4*)&Op[SS + off];
  f16x4 o;
#pragma unroll
  for (int j = 0; j < 4; ++j) o[j] = (f16)(w0 * (float)p0[j] + w1 * (float)p1[j]);
  *(f16x4*)&ath[off] = o;
}

// t = attn @ Wt with fused masked BN statistics (proven R4 version)
__global__ __launch_bounds__(256) void k_t(const f16* __restrict__ ah, const f16* __restrict__ WtT,
                                           const int* __restrict__ mask, float* __restrict__ t,
                                           float* __restrict__ sums) {
  __shared__ f16 sA[64 * 256];
  __shared__ float sSum[256];
  __shared__ float sSq[256];
  const int tid = threadIdx.x;
  const int lane = tid & 63;
  const int ln15 = lane & 15;
  const int quad = lane >> 4;
  const int wave = tid >> 6;
  const int wr = wave >> 1;
  const int wn = wave & 1;
  const size_t row0 = (size_t)blockIdx.x * 64;
  sSum[tid] = 0.f;
  sSq[tid] = 0.f;
  {
    const f16* src = ah + row0 * Dn;
#pragma unroll
    for (int i = 0; i < 8; ++i) {
      int flat = i * 256 + tid;
      int r = flat >> 5, p = flat & 31, g = p ^ (r & 7);
      async_ld16(&sA[(i * 256 + (tid & 192)) * 8], src + r * 256 + g * 8);
    }
  }
  __syncthreads();
  f16x8 af[2][8];
#pragma unroll
  for (int rg = 0; rg < 2; ++rg) {
    int r = wr * 32 + rg * 16 + ln15;
    int sw = r & 7;
#pragma unroll
    for (int c = 0; c < 8; ++c)
      af[rg][c] = *(const f16x8*)&sA[r * 256 + (((c * 4 + quad) ^ sw) << 3)];
  }
  f32x4 acc0[8], acc1[8];
#pragma unroll
  for (int nt = 0; nt < 8; ++nt) {
#pragma unroll
    for (int i = 0; i < 4; ++i) { acc0[nt][i] = 0.f; acc1[nt][i] = 0.f; }
  }
#pragma unroll
  for (int c = 0; c < 8; ++c) {
#pragma unroll
    for (int nt = 0; nt < 8; ++nt) {
      f16x8 bf = *(const f16x8*)&WtT[(size_t)(wn * 128 + nt * 16 + ln15) * 256 + c * 32 + quad * 8];
      acc0[nt] = __builtin_amdgcn_mfma_f32_16x16x32_f16(af[0][c], bf, acc0[nt], 0, 0, 0);
      acc1[nt] = __builtin_amdgcn_mfma_f32_16x16x32_f16(af[1][c], bf, acc1[nt], 0, 0, 0);
    }
  }
  float msk0[4], msk1[4];
#pragma unroll
  for (int i = 0; i < 4; ++i) {
    size_t r = row0 + wr * 32 + quad * 4 + i;
    msk0[i] = (mask[r] != 0) ? 1.f : 0.f;
    msk1[i] = (mask[r + 16] != 0) ? 1.f : 0.f;
  }
#pragma unroll
  for (int nt = 0; nt < 8; ++nt) {
    int col = wn * 128 + nt * 16 + ln15;
    float ps = 0.f, pq = 0.f;
#pragma unroll
    for (int i = 0; i < 4; ++i) {
      float v0 = acc0[nt][i], v1 = acc1[nt][i];
      t[(row0 + wr * 32 + quad * 4 + i) * (size_t)Dn + col] = v0;
      t[(row0 + wr * 32 + 16 + quad * 4 + i) * (size_t)Dn + col] = v1;
      ps += v0 * msk0[i] + v1 * msk1[i];
      pq += v0 * v0 * msk0[i] + v1 * v1 * msk1[i];
    }
    ps += __shfl_xor(ps, 16); ps += __shfl_xor(ps, 32);
    pq += __shfl_xor(pq, 16); pq += __shfl_xor(pq, 32);
    if (quad == 0) {
      atomicAdd(&sSum[col], ps);
      atomicAdd(&sSq[col], pq);
    }
  }
  __syncthreads();
  atomicAdd(&sums[tid], sSum[tid]);
  atomicAdd(&sums[256 + tid], sSq[tid]);
}

__device__ __forceinline__ float bn_relu(float tv, int ch, float fn, const float* sums,
                                         const float* gamma, const float* beta) {
  float mean = sums[ch] / fn;
  float var = sums[256 + ch] / fn - mean * mean;
  float y = gamma[ch] * (tv - mean) * rsqrtf(var + 1e-4f) + beta[ch];
  return y > 0.f ? y : 0.f;
}

__global__ __launch_bounds__(256) void k_final(const float* __restrict__ x, const int* __restrict__ mask,
                                               const float* __restrict__ t, const float* __restrict__ gamma,
                                               const float* __restrict__ beta, const float* __restrict__ sums,
                                               const int* __restrict__ lens, float* __restrict__ out) {
  const size_t idx = (size_t)blockIdx.x * 256 + threadIdx.x;
  const size_t row = idx >> 6;
  const int c = (int)(idx & 63) * 4;
  float4 o;
  if (mask[row] == 0) {
    o = make_float4(0.f, 0.f, 0.f, 0.f);
  } else {
    int n = 0;
#pragma unroll
    for (int i = 0; i < 8; ++i) n += lens[i];
    const float fn = (float)n;
    float4 tv = *(const float4*)&t[row * Dn + c];
    float4 xv = *(const float4*)&x[row * Dn + c];
    o.x = xv.x + bn_relu(tv.x, c + 0, fn, sums, gamma, beta);
    o.y = xv.y + bn_relu(tv.y, c + 1, fn, sums, gamma, beta);
    o.z = xv.z + bn_relu(tv.z, c + 2, fn, sums, gamma, beta);
    o.w = xv.w + bn_relu(tv.w, c + 3, fn, sums, gamma, beta);
  }
  *(float4*)&out[idx * 4] = o;
}

extern "C" void kernel_launch(void* const* d_in, const int* in_sizes, int n_in,
                              void* d_out, int out_size, void* d_ws, size_t ws_size,
                              hipStream_t stream) {
  const float* x = (const float*)d_in[0];
  const int* mask = (const int*)d_in[1];
  const float* Wq = (const float*)d_in[2];
  const float* Wk = (const float*)d_in[3];
  const float* Wv = (const float*)d_in[4];
  const float* Wt = (const float*)d_in[5];
  const float* gamma = (const float*)d_in[6];
  const float* beta = (const float*)d_in[7];
  float* out = (float*)d_out;
  char* wsb = (char*)d_ws;

  f16* Qh = (f16*)(wsb + B_QH);
  f16* Kh = (f16*)(wsb + B_KH);
  f16* Vt = (f16*)(wsb + B_VT);
  f16* Op = (f16*)(wsb + B_OP);
  float2* Ml = (float2*)(wsb + B_ML);
  f16* ath = (f16*)(wsb + B_ATH);
  float* t = (float*)(wsb + B_T);
  int* lens = (int*)(wsb + B_LENS);
  float* sums = (float*)(wsb + B_SUMS);
  f16* WqT = (f16*)(wsb + B_WQT);
  f16* WkT = (f16*)(wsb + B_WKT);
  f16* WvT = (f16*)(wsb + B_WVT);
  f16* WtT = (f16*)(wsb + B_WTT);

  k_init<<<8, 256, 0, stream>>>(mask, lens, sums);
  k_cast_w<<<dim3(4, 4, 4), 256, 0, stream>>>(Wq, Wk, Wv, Wt, WqT, WkT, WvT, WtT);
  k_qkv<<<512, 256, 0, stream>>>(x, WqT, WkT, WvT, Qh, Kh, Vt);
  k_flash<<<dim3(32, 2, 8), 256, 0, stream>>>(Qh, Kh, Vt, lens, Op, Ml);
  k_combine<<<8192, 256, 0, stream>>>(Op, Ml, lens, ath);   // ath overlays Qh (dead)
  k_t<<<512, 256, 0, stream>>>(ath, WtT, mask, t, sums);    // t overlays Kh/Vt (dead)
  k_final<<<8192, 256, 0, stream>>>(x, mask, t, gamma, beta, sums, lens, out);
}

// Round 6
// 463.242 us; speedup vs baseline: 1.4371x; 1.4371x over previous
//
#include <hip/hip_runtime.h>
#include <cmath>

typedef _Float16 f16;
typedef f16 f16x8 __attribute__((ext_vector_type(8)));
typedef f16 f16x4 __attribute__((ext_vector_type(4)));
typedef float f32x4 __attribute__((ext_vector_type(4)));

#define Ln 4096
#define Dn 256
#define NEGV (-1e30f)

// workspace byte offsets (~81.6 MiB; 96 MiB proven available)
#define B_QH   0ul           // fp16 Q = 16MiB (dead after flash; ath overlays)
#define B_KH   (16ul << 20)  // fp16 K = 16MiB (dead after flash; t overlays)
#define B_VT   (32ul << 20)  // fp16 V^T [8][256][4096] = 16MiB (dead after flash)
#define B_OP   (48ul << 20)  // fp16 partial O, 2 splits x 16MiB = 32MiB
#define B_ML   (80ul << 20)  // float2 (m,l) [2][8][4096] = 512KiB
#define B_ATH  0ul           // fp16 attn = 16MiB, overlays Qh
#define B_T    (16ul << 20)  // fp32 t = 32MiB, overlays Kh+Vt
#define B_LENS (81ul << 20)  // lens[8]
#define B_SUMS (B_LENS + 128)         // 512 floats
#define B_WQT  (B_LENS + 4096)        // fp16 WqT [256n][256k] = 128KiB
#define B_WKT  (B_WQT + (128ul<<10))
#define B_WVT  (B_WKT + (128ul<<10))
#define B_WTT  (B_WVT + (128ul<<10))

__device__ __forceinline__ void async_ld16(f16* lds, const f16* g) {
  __builtin_amdgcn_global_load_lds((const __attribute__((address_space(1))) unsigned int*)g,
                                   (__attribute__((address_space(3))) unsigned int*)lds, 16, 0, 0);
}

__global__ __launch_bounds__(256) void k_init(const int* __restrict__ mask, int* __restrict__ lens,
                                              float* __restrict__ sums) {
  const int b = blockIdx.x, tid = threadIdx.x;
  if (b == 0) { sums[tid] = 0.f; sums[256 + tid] = 0.f; }
  int cnt = 0;
  for (int l = tid; l < Ln; l += 256) cnt += (mask[b * Ln + l] != 0) ? 1 : 0;
  __shared__ int red[256];
  red[tid] = cnt;
  __syncthreads();
  for (int s = 128; s > 0; s >>= 1) {
    if (tid < s) red[tid] += red[tid + s];
    __syncthreads();
  }
  if (tid == 0) lens[b] = red[0];
}

// transpose+cast weights: WT[n][k] = (f16)W[k][n]
__global__ __launch_bounds__(256) void k_cast_w(const float* __restrict__ W0, const float* __restrict__ W1,
                                                const float* __restrict__ W2, const float* __restrict__ W3,
                                                f16* __restrict__ T0, f16* __restrict__ T1,
                                                f16* __restrict__ T2, f16* __restrict__ T3) {
  const float* Ws[4] = {W0, W1, W2, W3};
  f16* Ts[4] = {T0, T1, T2, T3};
  const float* W = Ws[blockIdx.x];
  f16* T = Ts[blockIdx.x];
  const int k0 = blockIdx.y * 64, n0 = blockIdx.z * 64;
  const int tid = threadIdx.x;
  __shared__ float ld[64][65];
#pragma unroll
  for (int i = 0; i < 16; ++i) {
    int flat = i * 256 + tid;
    int r = flat >> 6, c = flat & 63;
    ld[r][c] = W[(size_t)(k0 + r) * Dn + n0 + c];
  }
  __syncthreads();
#pragma unroll
  for (int i = 0; i < 16; ++i) {
    int flat = i * 256 + tid;
    int r = flat >> 6, c = flat & 63;
    T[(size_t)(n0 + r) * Dn + k0 + c] = (f16)ld[c][r];
  }
}

// Fused x-cast + QKV projection (proven R4/R5 version).
__global__ __launch_bounds__(256) void k_qkv(const float* __restrict__ x, const f16* __restrict__ WqT,
                                             const f16* __restrict__ WkT, const f16* __restrict__ WvT,
                                             f16* __restrict__ Qh, f16* __restrict__ Kh,
                                             f16* __restrict__ Vt) {
  __shared__ f16 sA[64 * 256];
  __shared__ f16 vts[256 * 72];
  const int tid = threadIdx.x;
  const int lane = tid & 63;
  const int ln15 = lane & 15;
  const int quad = lane >> 4;
  const int wave = tid >> 6;
  const int wr = wave >> 1;
  const int wn = wave & 1;
  const size_t row0 = (size_t)blockIdx.x * 64;

  {
    const float* src = x + row0 * Dn;
#pragma unroll
    for (int i = 0; i < 8; ++i) {
      int flat = i * 256 + tid;
      int r = flat >> 5, p = flat & 31, g = p ^ (r & 7);
      float4 lo = *(const float4*)&src[r * Dn + g * 8];
      float4 hi = *(const float4*)&src[r * Dn + g * 8 + 4];
      f16x8 h = {(f16)lo.x, (f16)lo.y, (f16)lo.z, (f16)lo.w,
                 (f16)hi.x, (f16)hi.y, (f16)hi.z, (f16)hi.w};
      *(f16x8*)&sA[flat * 8] = h;
    }
  }
  __syncthreads();

  f16x8 af[2][8];
#pragma unroll
  for (int rg = 0; rg < 2; ++rg) {
    int r = wr * 32 + rg * 16 + ln15;
    int sw = r & 7;
#pragma unroll
    for (int c = 0; c < 8; ++c)
      af[rg][c] = *(const f16x8*)&sA[r * 256 + (((c * 4 + quad) ^ sw) << 3)];
  }

  const f16* Bm[3] = {WqT, WkT, WvT};
  for (int m = 0; m < 3; ++m) {
    const f16* B = Bm[m];
    f32x4 acc0[8], acc1[8];
#pragma unroll
    for (int nt = 0; nt < 8; ++nt) {
#pragma unroll
      for (int i = 0; i < 4; ++i) { acc0[nt][i] = 0.f; acc1[nt][i] = 0.f; }
    }
#pragma unroll
    for (int c = 0; c < 8; ++c) {
#pragma unroll
      for (int nt = 0; nt < 8; ++nt) {
        f16x8 bf = *(const f16x8*)&B[(size_t)(wn * 128 + nt * 16 + ln15) * 256 + c * 32 + quad * 8];
        acc0[nt] = __builtin_amdgcn_mfma_f32_16x16x32_f16(af[0][c], bf, acc0[nt], 0, 0, 0);
        acc1[nt] = __builtin_amdgcn_mfma_f32_16x16x32_f16(af[1][c], bf, acc1[nt], 0, 0, 0);
      }
    }
    if (m < 2) {
      f16* dst = (m == 0) ? Qh : Kh;
#pragma unroll
      for (int nt = 0; nt < 8; ++nt) {
        int col = wn * 128 + nt * 16 + ln15;
#pragma unroll
        for (int i = 0; i < 4; ++i) {
          dst[(row0 + wr * 32 + quad * 4 + i) * (size_t)Dn + col] = (f16)acc0[nt][i];
          dst[(row0 + wr * 32 + 16 + quad * 4 + i) * (size_t)Dn + col] = (f16)acc1[nt][i];
        }
      }
    } else {
#pragma unroll
      for (int nt = 0; nt < 8; ++nt) {
        int ch = wn * 128 + nt * 16 + ln15;
#pragma unroll
        for (int i = 0; i < 4; ++i) {
          vts[ch * 72 + wr * 32 + quad * 4 + i] = (f16)acc0[nt][i];
          vts[ch * 72 + wr * 32 + 16 + quad * 4 + i] = (f16)acc1[nt][i];
        }
      }
      __syncthreads();
      const int b = (int)(row0 >> 12);
      const int l0 = (int)(row0 & 4095);
      f16* vdst = Vt + (size_t)b * Dn * Ln + (size_t)tid * Ln + l0;
#pragma unroll
      for (int j = 0; j < 8; ++j)
        *(f16x8*)(vdst + 8 * j) = *(const f16x8*)&vts[tid * 72 + 8 * j];
    }
  }
}

// Flash attention v4: 64q/block, 4 fully-independent waves x 16q x 256ch,
// 32-key single-buffered tiles, 2 barriers/tile, wave-local softmax,
// wave-private P round-trip. 2-way key split for block count.
// VGPR budget honest (~140): oAcc 64 + qf 32 + state; LDS 38KiB -> 3 blocks/CU.
__global__ __launch_bounds__(256, 3) void k_flash(const f16* __restrict__ Qh, const f16* __restrict__ Kh,
                                                  const f16* __restrict__ Vt, const int* __restrict__ lens,
                                                  f16* __restrict__ Op, float2* __restrict__ Ml) {
  const int b = blockIdx.z;
  const int s = blockIdx.y;
  const int len = lens[b];
  const int i0 = blockIdx.x * 64;
  if (i0 >= len) return;
  const int tid = threadIdx.x;
  const int lane = tid & 63;
  const int ln15 = lane & 15;
  const int quad = lane >> 4;
  const int w = tid >> 6;

  __shared__ f16 sK[32 * 256];   // 16 KiB, XOR-swizzled 16B granules
  __shared__ f16 sV[256 * 32];   // 16 KiB, V^T [ch][key], swizzled
  __shared__ f16 sP[4][16 * 40]; // wave-private P tiles (16q x 32k)

  const f16* Qb = Qh + (size_t)b * Ln * Dn;
  const f16* Kb = Kh + (size_t)b * Ln * Dn;
  const f16* Vb = Vt + (size_t)b * Dn * Ln;

  const int T = (len + 31) >> 5;
  const int h = T >> 1;
  const int t0 = s ? h : 0;
  const int t1 = s ? T : h;

  // Q A-fragments for this wave's 16 rows (rows i0 + w*16 + ln15)
  f16x8 qf[8];
  {
    const f16* qrow = Qb + (size_t)(i0 + w * 16 + ln15) * Dn + quad * 8;
#pragma unroll
    for (int c = 0; c < 8; ++c) qf[c] = *(const f16x8*)(qrow + c * 32);
  }

  f32x4 oAcc[16];
#pragma unroll
  for (int nf = 0; nf < 16; ++nf) { oAcc[nf][0] = 0.f; oAcc[nf][1] = 0.f; oAcc[nf][2] = 0.f; oAcc[nf][3] = 0.f; }
  float m_i[4], l_i[4];
#pragma unroll
  for (int i = 0; i < 4; ++i) { m_i[i] = -INFINITY; l_i[i] = 0.f; }

  for (int t = t0; t < t1; ++t) {
    const int j0 = t << 5;
    __syncthreads();  // all waves done reading sK/sV of previous tile
    {
      const f16* ksrc = Kb + (size_t)j0 * Dn;
#pragma unroll
      for (int i = 0; i < 4; ++i) {
        int flat = i * 256 + tid;
        int r = flat >> 5, p = flat & 31, g = p ^ (r & 7);
        async_ld16(&sK[(i * 256 + (tid & 192)) * 8], ksrc + r * Dn + g * 8);
      }
#pragma unroll
      for (int i = 0; i < 4; ++i) {
        int flat = i * 256 + tid;
        int r = flat >> 2, p = flat & 3, g = p ^ (r & 3);
        async_ld16(&sV[(i * 256 + (tid & 192)) * 8], Vb + (size_t)r * Ln + j0 + g * 8);
      }
    }
    __syncthreads();  // staged data visible (vmcnt drained by barrier semantics)

    // ---- S = Q K^T (16q x 32k per wave) ----
    f32x4 sa0, sa1;
    sa0[0] = sa0[1] = sa0[2] = sa0[3] = 0.f;
    sa1[0] = sa1[1] = sa1[2] = sa1[3] = 0.f;
    const int swz = ln15 & 7;
#pragma unroll
    for (int c = 0; c < 8; ++c) {
      int gk = (((c * 4 + quad) ^ swz) << 3);
      f16x8 b0 = *(const f16x8*)&sK[ln15 * 256 + gk];
      f16x8 b1 = *(const f16x8*)&sK[(16 + ln15) * 256 + gk];
      sa0 = __builtin_amdgcn_mfma_f32_16x16x32_f16(qf[c], b0, sa0, 0, 0, 0);
      sa1 = __builtin_amdgcn_mfma_f32_16x16x32_f16(qf[c], b1, sa1, 0, 0, 0);
    }

    // ---- online softmax (wave-local) ----
    const bool iv0 = (j0 + ln15) >= len;
    const bool iv1 = (j0 + 16 + ln15) >= len;
    float alpha[4];
    bool need = false;
#pragma unroll
    for (int i = 0; i < 4; ++i) {
      float a0 = iv0 ? NEGV : sa0[i];
      float a1 = iv1 ? NEGV : sa1[i];
      float rm = fmaxf(a0, a1);
      rm = fmaxf(rm, __shfl_xor(rm, 1));
      rm = fmaxf(rm, __shfl_xor(rm, 2));
      rm = fmaxf(rm, __shfl_xor(rm, 4));
      rm = fmaxf(rm, __shfl_xor(rm, 8));
      float mo = m_i[i];
      float mn = fmaxf(mo, rm);
      float al = __expf(mo - mn);
      float p0 = __expf(a0 - mn);
      float p1 = __expf(a1 - mn);
      float rs = p0 + p1;
      rs += __shfl_xor(rs, 1);
      rs += __shfl_xor(rs, 2);
      rs += __shfl_xor(rs, 4);
      rs += __shfl_xor(rs, 8);
      l_i[i] = l_i[i] * al + rs;
      m_i[i] = mn;
      alpha[i] = al;
      need |= (al < 1.0f);
      sP[w][(quad * 4 + i) * 40 + ln15] = (f16)p0;
      sP[w][(quad * 4 + i) * 40 + 16 + ln15] = (f16)p1;
    }
    if (__any(need ? 1 : 0)) {
#pragma unroll
      for (int nf = 0; nf < 16; ++nf)
#pragma unroll
        for (int i = 0; i < 4; ++i) oAcc[nf][i] *= alpha[i];
    }

    // ---- PV (16q x 256ch per wave, K=32) ----
    f16x8 pa = *(const f16x8*)&sP[w][ln15 * 40 + quad * 8];
#pragma unroll
    for (int nf = 0; nf < 16; ++nf) {
      int ch = nf * 16 + ln15;
      f16x8 vb = *(const f16x8*)&sV[ch * 32 + ((quad ^ (ch & 3)) << 3)];
      oAcc[nf] = __builtin_amdgcn_mfma_f32_16x16x32_f16(pa, vb, oAcc[nf], 0, 0, 0);
    }
  }

  // epilogue: normalized partial O + (m,l)
  f16* Ob = Op + ((size_t)s * 8 + b) * Ln * Dn;
  float2* Mb = Ml + ((size_t)s * 8 + b) * Ln;
#pragma unroll
  for (int i = 0; i < 4; ++i) {
    int row = i0 + w * 16 + quad * 4 + i;
    if (row < len) {
      float inv = 1.f / l_i[i];
#pragma unroll
      for (int nf = 0; nf < 16; ++nf)
        Ob[(size_t)row * Dn + nf * 16 + ln15] = (f16)(oAcc[nf][i] * inv);
      if (ln15 == 0) Mb[row] = make_float2(m_i[i], l_i[i]);
    }
  }
}

// merge the 2 key-split partials: out = sum_s w_s * O_s, w_s = exp(m_s-m*)*l_s (normalized)
__global__ __launch_bounds__(256) void k_combine(const f16* __restrict__ Op, const float2* __restrict__ Ml,
                                                 const int* __restrict__ lens, f16* __restrict__ ath) {
  const size_t idx = (size_t)blockIdx.x * 256 + threadIdx.x;  // f16x4 chunk
  const size_t rowg = idx >> 6;
  const int b = (int)(rowg >> 12);
  const int row = (int)(rowg & 4095);
  if (row >= lens[b]) return;
  const size_t SS = (size_t)8 * Ln * Dn;
  float2 ml0 = Ml[(size_t)b * Ln + row];
  float2 ml1 = Ml[(size_t)8 * Ln + (size_t)b * Ln + row];
  float ms = fmaxf(ml0.x, ml1.x);
  float w0 = __expf(ml0.x - ms) * ml0.y;
  float w1 = __expf(ml1.x - ms) * ml1.y;
  float inv = 1.f / (w0 + w1);
  w0 *= inv; w1 *= inv;
  const size_t off = rowg * Dn + (idx & 63) * 4;
  f16x4 p0 = *(const f16x4*)&Op[off];
  f16x4 p1 = *(const f16x4*)&Op[SS + off];
  f16x4 o;
#pragma unroll
  for (int j = 0; j < 4; ++j) o[j] = (f16)(w0 * (float)p0[j] + w1 * (float)p1[j]);
  *(f16x4*)&ath[off] = o;
}

// t = attn @ Wt with fused masked BN statistics (proven R4/R5 version)
__global__ __launch_bounds__(256) void k_t(const f16* __restrict__ ah, const f16* __restrict__ WtT,
                                           const int* __restrict__ mask, float* __restrict__ t,
                                           float* __restrict__ sums) {
  __shared__ f16 sA[64 * 256];
  __shared__ float sSum[256];
  __shared__ float sSq[256];
  const int tid = threadIdx.x;
  const int lane = tid & 63;
  const int ln15 = lane & 15;
  const int quad = lane >> 4;
  const int wave = tid >> 6;
  const int wr = wave >> 1;
  const int wn = wave & 1;
  const size_t row0 = (size_t)blockIdx.x * 64;
  sSum[tid] = 0.f;
  sSq[tid] = 0.f;
  {
    const f16* src = ah + row0 * Dn;
#pragma unroll
    for (int i = 0; i < 8; ++i) {
      int flat = i * 256 + tid;
      int r = flat >> 5, p = flat & 31, g = p ^ (r & 7);
      async_ld16(&sA[(i * 256 + (tid & 192)) * 8], src + r * 256 + g * 8);
    }
  }
  __syncthreads();
  f16x8 af[2][8];
#pragma unroll
  for (int rg = 0; rg < 2; ++rg) {
    int r = wr * 32 + rg * 16 + ln15;
    int sw = r & 7;
#pragma unroll
    for (int c = 0; c < 8; ++c)
      af[rg][c] = *(const f16x8*)&sA[r * 256 + (((c * 4 + quad) ^ sw) << 3)];
  }
  f32x4 acc0[8], acc1[8];
#pragma unroll
  for (int nt = 0; nt < 8; ++nt) {
#pragma unroll
    for (int i = 0; i < 4; ++i) { acc0[nt][i] = 0.f; acc1[nt][i] = 0.f; }
  }
#pragma unroll
  for (int c = 0; c < 8; ++c) {
#pragma unroll
    for (int nt = 0; nt < 8; ++nt) {
      f16x8 bf = *(const f16x8*)&WtT[(size_t)(wn * 128 + nt * 16 + ln15) * 256 + c * 32 + quad * 8];
      acc0[nt] = __builtin_amdgcn_mfma_f32_16x16x32_f16(af[0][c], bf, acc0[nt], 0, 0, 0);
      acc1[nt] = __builtin_amdgcn_mfma_f32_16x16x32_f16(af[1][c], bf, acc1[nt], 0, 0, 0);
    }
  }
  float msk0[4], msk1[4];
#pragma unroll
  for (int i = 0; i < 4; ++i) {
    size_t r = row0 + wr * 32 + quad * 4 + i;
    msk0[i] = (mask[r] != 0) ? 1.f : 0.f;
    msk1[i] = (mask[r + 16] != 0) ? 1.f : 0.f;
  }
#pragma unroll
  for (int nt = 0; nt < 8; ++nt) {
    int col = wn * 128 + nt * 16 + ln15;
    float ps = 0.f, pq = 0.f;
#pragma unroll
    for (int i = 0; i < 4; ++i) {
      float v0 = acc0[nt][i], v1 = acc1[nt][i];
      t[(row0 + wr * 32 + quad * 4 + i) * (size_t)Dn + col] = v0;
      t[(row0 + wr * 32 + 16 + quad * 4 + i) * (size_t)Dn + col] = v1;
      ps += v0 * msk0[i] + v1 * msk1[i];
      pq += v0 * v0 * msk0[i] + v1 * v1 * msk1[i];
    }
    ps += __shfl_xor(ps, 16); ps += __shfl_xor(ps, 32);
    pq += __shfl_xor(pq, 16); pq += __shfl_xor(pq, 32);
    if (quad == 0) {
      atomicAdd(&sSum[col], ps);
      atomicAdd(&sSq[col], pq);
    }
  }
  __syncthreads();
  atomicAdd(&sums[tid], sSum[tid]);
  atomicAdd(&sums[256 + tid], sSq[tid]);
}

__device__ __forceinline__ float bn_relu(float tv, int ch, float fn, const float* sums,
                                         const float* gamma, const float* beta) {
  float mean = sums[ch] / fn;
  float var = sums[256 + ch] / fn - mean * mean;
  float y = gamma[ch] * (tv - mean) * rsqrtf(var + 1e-4f) + beta[ch];
  return y > 0.f ? y : 0.f;
}

__global__ __launch_bounds__(256) void k_final(const float* __restrict__ x, const int* __restrict__ mask,
                                               const float* __restrict__ t, const float* __restrict__ gamma,
                                               const float* __restrict__ beta, const float* __restrict__ sums,
                                               const int* __restrict__ lens, float* __restrict__ out) {
  const size_t idx = (size_t)blockIdx.x * 256 + threadIdx.x;
  const size_t row = idx >> 6;
  const int c = (int)(idx & 63) * 4;
  float4 o;
  if (mask[row] == 0) {
    o = make_float4(0.f, 0.f, 0.f, 0.f);
  } else {
    int n = 0;
#pragma unroll
    for (int i = 0; i < 8; ++i) n += lens[i];
    const float fn = (float)n;
    float4 tv = *(const float4*)&t[row * Dn + c];
    float4 xv = *(const float4*)&x[row * Dn + c];
    o.x = xv.x + bn_relu(tv.x, c + 0, fn, sums, gamma, beta);
    o.y = xv.y + bn_relu(tv.y, c + 1, fn, sums, gamma, beta);
    o.z = xv.z + bn_relu(tv.z, c + 2, fn, sums, gamma, beta);
    o.w = xv.w + bn_relu(tv.w, c + 3, fn, sums, gamma, beta);
  }
  *(float4*)&out[idx * 4] = o;
}

extern "C" void kernel_launch(void* const* d_in, const int* in_sizes, int n_in,
                              void* d_out, int out_size, void* d_ws, size_t ws_size,
                              hipStream_t stream) {
  const float* x = (const float*)d_in[0];
  const int* mask = (const int*)d_in[1];
  const float* Wq = (const float*)d_in[2];
  const float* Wk = (const float*)d_in[3];
  const float* Wv = (const float*)d_in[4];
  const float* Wt = (const float*)d_in[5];
  const float* gamma = (const float*)d_in[6];
  const float* beta = (const float*)d_in[7];
  float* out = (float*)d_out;
  char* wsb = (char*)d_ws;

  f16* Qh = (f16*)(wsb + B_QH);
  f16* Kh = (f16*)(wsb + B_KH);
  f16* Vt = (f16*)(wsb + B_VT);
  f16* Op = (f16*)(wsb + B_OP);
  float2* Ml = (float2*)(wsb + B_ML);
  f16* ath = (f16*)(wsb + B_ATH);
  float* t = (float*)(wsb + B_T);
  int* lens = (int*)(wsb + B_LENS);
  float* sums = (float*)(wsb + B_SUMS);
  f16* WqT = (f16*)(wsb + B_WQT);
  f16* WkT = (f16*)(wsb + B_WKT);
  f16* WvT = (f16*)(wsb + B_WVT);
  f16* WtT = (f16*)(wsb + B_WTT);

  k_init<<<8, 256, 0, stream>>>(mask, lens, sums);
  k_cast_w<<<dim3(4, 4, 4), 256, 0, stream>>>(Wq, Wk, Wv, Wt, WqT, WkT, WvT, WtT);
  k_qkv<<<512, 256, 0, stream>>>(x, WqT, WkT, WvT, Qh, Kh, Vt);
  k_flash<<<dim3(64, 2, 8), 256, 0, stream>>>(Qh, Kh, Vt, lens, Op, Ml);
  k_combine<<<8192, 256, 0, stream>>>(Op, Ml, lens, ath);   // ath overlays Qh (dead)
  k_t<<<512, 256, 0, stream>>>(ath, WtT, mask, t, sums);    // t overlays Kh/Vt (dead)
  k_final<<<8192, 256, 0, stream>>>(x, mask, t, gamma, beta, sums, lens, out);
}

// Round 7
// 395.034 us; speedup vs baseline: 1.6853x; 1.1727x over previous
//
#include <hip/hip_runtime.h>
#include <cmath>

typedef _Float16 f16;
typedef f16 f16x8 __attribute__((ext_vector_type(8)));
typedef f16 f16x4 __attribute__((ext_vector_type(4)));
typedef float f32x4 __attribute__((ext_vector_type(4)));

#define Ln 4096
#define Dn 256
#define NEGV (-1e30f)

// workspace byte offsets (~97.6 MiB; 100.7 MiB proven in R1)
#define B_QH   0ul           // fp16 Q = 16MiB (live through flash)
#define B_KH   (16ul << 20)  // fp16 K = 16MiB (dead after flash; t overlays)
#define B_VT   (32ul << 20)  // fp16 V^T [8][256][4096] = 16MiB (dead after flash)
#define B_OP   (48ul << 20)  // fp16 partial O, 3 splits x 16MiB = 48MiB
#define B_ML   (96ul << 20)  // float2 (m,l) [3][8][4096] = 768KiB
#define B_T    (16ul << 20)  // fp32 t = 32MiB, overlays Kh+Vt
#define B_LENS ((97ul << 20))
#define B_SUMS (B_LENS + 128)         // 512 floats
#define B_WQT  (B_LENS + 4096)        // fp16 WqT [256n][256k] = 128KiB
#define B_WKT  (B_WQT + (128ul<<10))
#define B_WVT  (B_WKT + (128ul<<10))
#define B_WTT  (B_WVT + (128ul<<10))

__device__ __forceinline__ void async_ld16(f16* lds, const f16* g) {
  __builtin_amdgcn_global_load_lds((const __attribute__((address_space(1))) unsigned int*)g,
                                   (__attribute__((address_space(3))) unsigned int*)lds, 16, 0, 0);
}

__global__ __launch_bounds__(256) void k_init(const int* __restrict__ mask, int* __restrict__ lens,
                                              float* __restrict__ sums) {
  const int b = blockIdx.x, tid = threadIdx.x;
  if (b == 0) { sums[tid] = 0.f; sums[256 + tid] = 0.f; }
  int cnt = 0;
  for (int l = tid; l < Ln; l += 256) cnt += (mask[b * Ln + l] != 0) ? 1 : 0;
  __shared__ int red[256];
  red[tid] = cnt;
  __syncthreads();
  for (int s = 128; s > 0; s >>= 1) {
    if (tid < s) red[tid] += red[tid + s];
    __syncthreads();
  }
  if (tid == 0) lens[b] = red[0];
}

// transpose+cast weights: WT[n][k] = (f16)W[k][n]
__global__ __launch_bounds__(256) void k_cast_w(const float* __restrict__ W0, const float* __restrict__ W1,
                                                const float* __restrict__ W2, const float* __restrict__ W3,
                                                f16* __restrict__ T0, f16* __restrict__ T1,
                                                f16* __restrict__ T2, f16* __restrict__ T3) {
  const float* Ws[4] = {W0, W1, W2, W3};
  f16* Ts[4] = {T0, T1, T2, T3};
  const float* W = Ws[blockIdx.x];
  f16* T = Ts[blockIdx.x];
  const int k0 = blockIdx.y * 64, n0 = blockIdx.z * 64;
  const int tid = threadIdx.x;
  __shared__ float ld[64][65];
#pragma unroll
  for (int i = 0; i < 16; ++i) {
    int flat = i * 256 + tid;
    int r = flat >> 6, c = flat & 63;
    ld[r][c] = W[(size_t)(k0 + r) * Dn + n0 + c];
  }
  __syncthreads();
#pragma unroll
  for (int i = 0; i < 16; ++i) {
    int flat = i * 256 + tid;
    int r = flat >> 6, c = flat & 63;
    T[(size_t)(n0 + r) * Dn + k0 + c] = (f16)ld[c][r];
  }
}

// Fused x-cast + QKV projection (proven R4-R6 version).
__global__ __launch_bounds__(256) void k_qkv(const float* __restrict__ x, const f16* __restrict__ WqT,
                                             const f16* __restrict__ WkT, const f16* __restrict__ WvT,
                                             f16* __restrict__ Qh, f16* __restrict__ Kh,
                                             f16* __restrict__ Vt) {
  __shared__ f16 sA[64 * 256];
  __shared__ f16 vts[256 * 72];
  const int tid = threadIdx.x;
  const int lane = tid & 63;
  const int ln15 = lane & 15;
  const int quad = lane >> 4;
  const int wave = tid >> 6;
  const int wr = wave >> 1;
  const int wn = wave & 1;
  const size_t row0 = (size_t)blockIdx.x * 64;

  {
    const float* src = x + row0 * Dn;
#pragma unroll
    for (int i = 0; i < 8; ++i) {
      int flat = i * 256 + tid;
      int r = flat >> 5, p = flat & 31, g = p ^ (r & 7);
      float4 lo = *(const float4*)&src[r * Dn + g * 8];
      float4 hi = *(const float4*)&src[r * Dn + g * 8 + 4];
      f16x8 h = {(f16)lo.x, (f16)lo.y, (f16)lo.z, (f16)lo.w,
                 (f16)hi.x, (f16)hi.y, (f16)hi.z, (f16)hi.w};
      *(f16x8*)&sA[flat * 8] = h;
    }
  }
  __syncthreads();

  f16x8 af[2][8];
#pragma unroll
  for (int rg = 0; rg < 2; ++rg) {
    int r = wr * 32 + rg * 16 + ln15;
    int sw = r & 7;
#pragma unroll
    for (int c = 0; c < 8; ++c)
      af[rg][c] = *(const f16x8*)&sA[r * 256 + (((c * 4 + quad) ^ sw) << 3)];
  }

  const f16* Bm[3] = {WqT, WkT, WvT};
  for (int m = 0; m < 3; ++m) {
    const f16* B = Bm[m];
    f32x4 acc0[8], acc1[8];
#pragma unroll
    for (int nt = 0; nt < 8; ++nt) {
#pragma unroll
      for (int i = 0; i < 4; ++i) { acc0[nt][i] = 0.f; acc1[nt][i] = 0.f; }
    }
#pragma unroll
    for (int c = 0; c < 8; ++c) {
#pragma unroll
      for (int nt = 0; nt < 8; ++nt) {
        f16x8 bf = *(const f16x8*)&B[(size_t)(wn * 128 + nt * 16 + ln15) * 256 + c * 32 + quad * 8];
        acc0[nt] = __builtin_amdgcn_mfma_f32_16x16x32_f16(af[0][c], bf, acc0[nt], 0, 0, 0);
        acc1[nt] = __builtin_amdgcn_mfma_f32_16x16x32_f16(af[1][c], bf, acc1[nt], 0, 0, 0);
      }
    }
    if (m < 2) {
      f16* dst = (m == 0) ? Qh : Kh;
#pragma unroll
      for (int nt = 0; nt < 8; ++nt) {
        int col = wn * 128 + nt * 16 + ln15;
#pragma unroll
        for (int i = 0; i < 4; ++i) {
          dst[(row0 + wr * 32 + quad * 4 + i) * (size_t)Dn + col] = (f16)acc0[nt][i];
          dst[(row0 + wr * 32 + 16 + quad * 4 + i) * (size_t)Dn + col] = (f16)acc1[nt][i];
        }
      }
    } else {
#pragma unroll
      for (int nt = 0; nt < 8; ++nt) {
        int ch = wn * 128 + nt * 16 + ln15;
#pragma unroll
        for (int i = 0; i < 4; ++i) {
          vts[ch * 72 + wr * 32 + quad * 4 + i] = (f16)acc0[nt][i];
          vts[ch * 72 + wr * 32 + 16 + quad * 4 + i] = (f16)acc1[nt][i];
        }
      }
      __syncthreads();
      const int b = (int)(row0 >> 12);
      const int l0 = (int)(row0 & 4095);
      f16* vdst = Vt + (size_t)b * Dn * Ln + (size_t)tid * Ln + l0;
#pragma unroll
      for (int j = 0; j < 8; ++j)
        *(f16x8*)(vdst + 8 * j) = *(const f16x8*)&vts[tid * 72 + 8 * j];
    }
  }
}

// Flash attention v5: 64q/block, 4 independent waves x 16q x 256ch, 32-key
// single-buffered tiles, 2 barriers/tile, wave-local softmax with MFMA row-sum
// for l (P x ones). 3-way key split -> 1152 active blocks vs 768 residency
// slots: continuous block replacement evens the len-imbalance tail.
__global__ __launch_bounds__(256, 3) void k_flash(const f16* __restrict__ Qh, const f16* __restrict__ Kh,
                                                  const f16* __restrict__ Vt, const int* __restrict__ lens,
                                                  f16* __restrict__ Op, float2* __restrict__ Ml) {
  const int b = blockIdx.z;
  const int s = blockIdx.y;
  const int len = lens[b];
  const int i0 = blockIdx.x * 64;
  if (i0 >= len) return;
  const int tid = threadIdx.x;
  const int lane = tid & 63;
  const int ln15 = lane & 15;
  const int quad = lane >> 4;
  const int w = tid >> 6;

  __shared__ f16 sK[32 * 256];   // 16 KiB, XOR-swizzled 16B granules
  __shared__ f16 sV[256 * 32];   // 16 KiB, V^T [ch][key], swizzled
  __shared__ f16 sP[4][16 * 40]; // wave-private P tiles (16q x 32k)

  const f16* Qb = Qh + (size_t)b * Ln * Dn;
  const f16* Kb = Kh + (size_t)b * Ln * Dn;
  const f16* Vb = Vt + (size_t)b * Dn * Ln;

  const int T = (len + 31) >> 5;
  const int t0 = (s * T) / 3;
  const int t1 = ((s + 1) * T) / 3;

  // Q A-fragments for this wave's 16 rows
  f16x8 qf[8];
  {
    const f16* qrow = Qb + (size_t)(i0 + w * 16 + ln15) * Dn + quad * 8;
#pragma unroll
    for (int c = 0; c < 8; ++c) qf[c] = *(const f16x8*)(qrow + c * 32);
  }

  f32x4 oAcc[16];
#pragma unroll
  for (int nf = 0; nf < 16; ++nf) { oAcc[nf][0] = 0.f; oAcc[nf][1] = 0.f; oAcc[nf][2] = 0.f; oAcc[nf][3] = 0.f; }
  f32x4 lAcc;
  lAcc[0] = lAcc[1] = lAcc[2] = lAcc[3] = 0.f;
  float m_i[4];
#pragma unroll
  for (int i = 0; i < 4; ++i) m_i[i] = -INFINITY;
  const f16x8 onesf = {(f16)1.f, (f16)1.f, (f16)1.f, (f16)1.f,
                       (f16)1.f, (f16)1.f, (f16)1.f, (f16)1.f};

  for (int t = t0; t < t1; ++t) {
    const int j0 = t << 5;
    __syncthreads();  // all waves done reading sK/sV of previous tile
    {
      const f16* ksrc = Kb + (size_t)j0 * Dn;
#pragma unroll
      for (int i = 0; i < 4; ++i) {
        int flat = i * 256 + tid;
        int r = flat >> 5, p = flat & 31, g = p ^ (r & 7);
        async_ld16(&sK[(i * 256 + (tid & 192)) * 8], ksrc + r * Dn + g * 8);
      }
#pragma unroll
      for (int i = 0; i < 4; ++i) {
        int flat = i * 256 + tid;
        int r = flat >> 2, p = flat & 3, g = p ^ (r & 3);
        async_ld16(&sV[(i * 256 + (tid & 192)) * 8], Vb + (size_t)r * Ln + j0 + g * 8);
      }
    }
    __syncthreads();  // staged data visible

    // ---- S = Q K^T (16q x 32k per wave) ----
    f32x4 sa0, sa1;
    sa0[0] = sa0[1] = sa0[2] = sa0[3] = 0.f;
    sa1[0] = sa1[1] = sa1[2] = sa1[3] = 0.f;
    const int swz = ln15 & 7;
#pragma unroll
    for (int c = 0; c < 8; ++c) {
      int gk = (((c * 4 + quad) ^ swz) << 3);
      f16x8 b0 = *(const f16x8*)&sK[ln15 * 256 + gk];
      f16x8 b1 = *(const f16x8*)&sK[(16 + ln15) * 256 + gk];
      sa0 = __builtin_amdgcn_mfma_f32_16x16x32_f16(qf[c], b0, sa0, 0, 0, 0);
      sa1 = __builtin_amdgcn_mfma_f32_16x16x32_f16(qf[c], b1, sa1, 0, 0, 0);
    }

    // ---- online softmax (wave-local; max via shuffles, sum via MFMA) ----
    const bool iv0 = (j0 + ln15) >= len;
    const bool iv1 = (j0 + 16 + ln15) >= len;
    float alpha[4];
    bool need = false;
#pragma unroll
    for (int i = 0; i < 4; ++i) {
      float a0 = iv0 ? NEGV : sa0[i];
      float a1 = iv1 ? NEGV : sa1[i];
      float rm = fmaxf(a0, a1);
      rm = fmaxf(rm, __shfl_xor(rm, 1));
      rm = fmaxf(rm, __shfl_xor(rm, 2));
      rm = fmaxf(rm, __shfl_xor(rm, 4));
      rm = fmaxf(rm, __shfl_xor(rm, 8));
      float mo = m_i[i];
      float mn = fmaxf(mo, rm);
      float al = __expf(mo - mn);
      float p0 = __expf(a0 - mn);
      float p1 = __expf(a1 - mn);
      m_i[i] = mn;
      alpha[i] = al;
      need |= (al < 1.0f);
      sP[w][(quad * 4 + i) * 40 + ln15] = (f16)p0;
      sP[w][(quad * 4 + i) * 40 + 16 + ln15] = (f16)p1;
    }
    if (__any(need ? 1 : 0)) {
#pragma unroll
      for (int nf = 0; nf < 16; ++nf)
#pragma unroll
        for (int i = 0; i < 4; ++i) oAcc[nf][i] *= alpha[i];
#pragma unroll
      for (int i = 0; i < 4; ++i) lAcc[i] *= alpha[i];
    }

    // ---- PV (16q x 256ch per wave) + l row-sum via P x ones ----
    f16x8 pa = *(const f16x8*)&sP[w][ln15 * 40 + quad * 8];
    lAcc = __builtin_amdgcn_mfma_f32_16x16x32_f16(pa, onesf, lAcc, 0, 0, 0);
#pragma unroll
    for (int nf = 0; nf < 16; ++nf) {
      int ch = nf * 16 + ln15;
      f16x8 vb = *(const f16x8*)&sV[ch * 32 + ((quad ^ (ch & 3)) << 3)];
      oAcc[nf] = __builtin_amdgcn_mfma_f32_16x16x32_f16(pa, vb, oAcc[nf], 0, 0, 0);
    }
  }

  // epilogue: normalized partial O + (m,l)
  f16* Ob = Op + (size_t)s * (8ul * Ln * Dn) + (size_t)b * Ln * Dn;
  float2* Mb = Ml + ((size_t)s * 8 + b) * Ln;
#pragma unroll
  for (int i = 0; i < 4; ++i) {
    int row = i0 + w * 16 + quad * 4 + i;
    if (row < len) {
      float inv = 1.f / lAcc[i];
#pragma unroll
      for (int nf = 0; nf < 16; ++nf)
        Ob[(size_t)row * Dn + nf * 16 + ln15] = (f16)(oAcc[nf][i] * inv);
      if (ln15 == 0) Mb[row] = make_float2(m_i[i], lAcc[i]);
    }
  }
}

// t = (combined attn) @ Wt with fused 3-way split merge + masked BN statistics.
__global__ __launch_bounds__(256) void k_t(const f16* __restrict__ Op, const float2* __restrict__ Ml,
                                           const f16* __restrict__ WtT, const int* __restrict__ mask,
                                           const int* __restrict__ lens, float* __restrict__ t,
                                           float* __restrict__ sums) {
  __shared__ f16 sA[64 * 256];
  __shared__ float sW[3][64];
  __shared__ float sSum[256];
  __shared__ float sSq[256];
  const int tid = threadIdx.x;
  const int lane = tid & 63;
  const int ln15 = lane & 15;
  const int quad = lane >> 4;
  const int wave = tid >> 6;
  const int wr = wave >> 1;
  const int wn = wave & 1;
  const size_t row0 = (size_t)blockIdx.x * 64;
  const int b = (int)(row0 >> 12);
  const int r0loc = (int)(row0 & 4095);
  const size_t SS = 8ul * Ln * Dn;
  sSum[tid] = 0.f;
  sSq[tid] = 0.f;
  if (tid < 64) {
    int rl = r0loc + tid;
    float w0 = 0.f, w1 = 0.f, w2 = 0.f;
    if (rl < lens[b]) {
      float2 m0 = Ml[(size_t)(0 * 8 + b) * Ln + rl];
      float2 m1 = Ml[(size_t)(1 * 8 + b) * Ln + rl];
      float2 m2 = Ml[(size_t)(2 * 8 + b) * Ln + rl];
      float ms = fmaxf(m0.x, fmaxf(m1.x, m2.x));
      w0 = __expf(m0.x - ms) * m0.y;
      w1 = __expf(m1.x - ms) * m1.y;
      w2 = __expf(m2.x - ms) * m2.y;
      float inv = 1.f / (w0 + w1 + w2);
      w0 *= inv; w1 *= inv; w2 *= inv;
    }
    sW[0][tid] = w0; sW[1][tid] = w1; sW[2][tid] = w2;
  }
  __syncthreads();
  // merge-stage attn into swizzled sA
#pragma unroll
  for (int i = 0; i < 8; ++i) {
    int flat = i * 256 + tid;
    int r = flat >> 5, p = flat & 31, g = p ^ (r & 7);
    size_t off = (row0 + r) * (size_t)Dn + g * 8;
    f16x8 p0 = *(const f16x8*)&Op[off];
    f16x8 p1 = *(const f16x8*)&Op[SS + off];
    f16x8 p2 = *(const f16x8*)&Op[2 * SS + off];
    float w0 = sW[0][r], w1 = sW[1][r], w2 = sW[2][r];
    f16x8 h;
#pragma unroll
    for (int j = 0; j < 8; ++j)
      h[j] = (f16)(w0 * (float)p0[j] + w1 * (float)p1[j] + w2 * (float)p2[j]);
    *(f16x8*)&sA[flat * 8] = h;
  }
  __syncthreads();
  f16x8 af[2][8];
#pragma unroll
  for (int rg = 0; rg < 2; ++rg) {
    int r = wr * 32 + rg * 16 + ln15;
    int sw = r & 7;
#pragma unroll
    for (int c = 0; c < 8; ++c)
      af[rg][c] = *(const f16x8*)&sA[r * 256 + (((c * 4 + quad) ^ sw) << 3)];
  }
  f32x4 acc0[8], acc1[8];
#pragma unroll
  for (int nt = 0; nt < 8; ++nt) {
#pragma unroll
    for (int i = 0; i < 4; ++i) { acc0[nt][i] = 0.f; acc1[nt][i] = 0.f; }
  }
#pragma unroll
  for (int c = 0; c < 8; ++c) {
#pragma unroll
    for (int nt = 0; nt < 8; ++nt) {
      f16x8 bf = *(const f16x8*)&WtT[(size_t)(wn * 128 + nt * 16 + ln15) * 256 + c * 32 + quad * 8];
      acc0[nt] = __builtin_amdgcn_mfma_f32_16x16x32_f16(af[0][c], bf, acc0[nt], 0, 0, 0);
      acc1[nt] = __builtin_amdgcn_mfma_f32_16x16x32_f16(af[1][c], bf, acc1[nt], 0, 0, 0);
    }
  }
  float msk0[4], msk1[4];
#pragma unroll
  for (int i = 0; i < 4; ++i) {
    size_t r = row0 + wr * 32 + quad * 4 + i;
    msk0[i] = (mask[r] != 0) ? 1.f : 0.f;
    msk1[i] = (mask[r + 16] != 0) ? 1.f : 0.f;
  }
#pragma unroll
  for (int nt = 0; nt < 8; ++nt) {
    int col = wn * 128 + nt * 16 + ln15;
    float ps = 0.f, pq = 0.f;
#pragma unroll
    for (int i = 0; i < 4; ++i) {
      float v0 = acc0[nt][i], v1 = acc1[nt][i];
      t[(row0 + wr * 32 + quad * 4 + i) * (size_t)Dn + col] = v0;
      t[(row0 + wr * 32 + 16 + quad * 4 + i) * (size_t)Dn + col] = v1;
      ps += v0 * msk0[i] + v1 * msk1[i];
      pq += v0 * v0 * msk0[i] + v1 * v1 * msk1[i];
    }
    ps += __shfl_xor(ps, 16); ps += __shfl_xor(ps, 32);
    pq += __shfl_xor(pq, 16); pq += __shfl_xor(pq, 32);
    if (quad == 0) {
      atomicAdd(&sSum[col], ps);
      atomicAdd(&sSq[col], pq);
    }
  }
  __syncthreads();
  atomicAdd(&sums[tid], sSum[tid]);
  atomicAdd(&sums[256 + tid], sSq[tid]);
}

__device__ __forceinline__ float bn_relu(float tv, int ch, float fn, const float* sums,
                                         const float* gamma, const float* beta) {
  float mean = sums[ch] / fn;
  float var = sums[256 + ch] / fn - mean * mean;
  float y = gamma[ch] * (tv - mean) * rsqrtf(var + 1e-4f) + beta[ch];
  return y > 0.f ? y : 0.f;
}

__global__ __launch_bounds__(256) void k_final(const float* __restrict__ x, const int* __restrict__ mask,
                                               const float* __restrict__ t, const float* __restrict__ gamma,
                                               const float* __restrict__ beta, const float* __restrict__ sums,
                                               const int* __restrict__ lens, float* __restrict__ out) {
  const size_t idx = (size_t)blockIdx.x * 256 + threadIdx.x;
  const size_t row = idx >> 6;
  const int c = (int)(idx & 63) * 4;
  float4 o;
  if (mask[row] == 0) {
    o = make_float4(0.f, 0.f, 0.f, 0.f);
  } else {
    int n = 0;
#pragma unroll
    for (int i = 0; i < 8; ++i) n += lens[i];
    const float fn = (float)n;
    float4 tv = *(const float4*)&t[row * Dn + c];
    float4 xv = *(const float4*)&x[row * Dn + c];
    o.x = xv.x + bn_relu(tv.x, c + 0, fn, sums, gamma, beta);
    o.y = xv.y + bn_relu(tv.y, c + 1, fn, sums, gamma, beta);
    o.z = xv.z + bn_relu(tv.z, c + 2, fn, sums, gamma, beta);
    o.w = xv.w + bn_relu(tv.w, c + 3, fn, sums, gamma, beta);
  }
  *(float4*)&out[idx * 4] = o;
}

extern "C" void kernel_launch(void* const* d_in, const int* in_sizes, int n_in,
                              void* d_out, int out_size, void* d_ws, size_t ws_size,
                              hipStream_t stream) {
  const float* x = (const float*)d_in[0];
  const int* mask = (const int*)d_in[1];
  const float* Wq = (const float*)d_in[2];
  const float* Wk = (const float*)d_in[3];
  const float* Wv = (const float*)d_in[4];
  const float* Wt = (const float*)d_in[5];
  const float* gamma = (const float*)d_in[6];
  const float* beta = (const float*)d_in[7];
  float* out = (float*)d_out;
  char* wsb = (char*)d_ws;

  f16* Qh = (f16*)(wsb + B_QH);
  f16* Kh = (f16*)(wsb + B_KH);
  f16* Vt = (f16*)(wsb + B_VT);
  f16* Op = (f16*)(wsb + B_OP);
  float2* Ml = (float2*)(wsb + B_ML);
  float* t = (float*)(wsb + B_T);
  int* lens = (int*)(wsb + B_LENS);
  float* sums = (float*)(wsb + B_SUMS);
  f16* WqT = (f16*)(wsb + B_WQT);
  f16* WkT = (f16*)(wsb + B_WKT);
  f16* WvT = (f16*)(wsb + B_WVT);
  f16* WtT = (f16*)(wsb + B_WTT);

  k_init<<<8, 256, 0, stream>>>(mask, lens, sums);
  k_cast_w<<<dim3(4, 4, 4), 256, 0, stream>>>(Wq, Wk, Wv, Wt, WqT, WkT, WvT, WtT);
  k_qkv<<<512, 256, 0, stream>>>(x, WqT, WkT, WvT, Qh, Kh, Vt);
  k_flash<<<dim3(64, 3, 8), 256, 0, stream>>>(Qh, Kh, Vt, lens, Op, Ml);
  k_t<<<512, 256, 0, stream>>>(Op, Ml, WtT, mask, lens, t, sums);  // t overlays Kh/Vt (dead)
  k_final<<<8192, 256, 0, stream>>>(x, mask, t, gamma, beta, sums, lens, out);
}